// Round 10
// baseline (174.985 us; speedup 1.0000x reference)
//
#include <hip/hip_runtime.h>

// ResidualNetwork forward, MI355X (gfx950).
// Round 30: 4-CHAIN ASM, LATENCY FILLED WITH REAL WORK. r21-r29: ten kernels,
// one wall -- MfmaUtil x wall = 98-105k cyc/SIMD every round (pipe serves its
// demand at ~53% duty). Wave supply exonerated (r23: 8 w/SIMD guaranteed,
// same wall). Discriminating experiment between: (H-A) a wave CAN feed the
// pipe at 32cyc/MFMA if >=4 MFMAs are in flight with latency filled by real
// work (never yet achieved: r28's NOP19 windows issued nothing); (H-B) the
// pipe serves this mixed VGPR stream at ~64cyc/MFMA (196k cyc == the 82us
// wall exactly). Design: 4 independent chains/wave (TPW=16 = 4 iters x 4
// tiles); all chains at the SAME layer -> one shared A-plane reg set; each
// stage issues 4 MFMAs back-to-back, latency windows filled with other
// chains' repack. Per-stage wave-serial ~200cyc for 256 pipe-cyc of MFMA ->
// single wave oversupplies pipe 1.3x; 3 waves (reg-forced, bounds (256,3),
// cap 168: asm v16-127 + glue v0-15/v128-167, zero spill) -> 4x oversupply.
// Hazard distances inherited from r28 (validated absmax 0 under contention).
// Gates: absmax 0; VGPR 150-168; FETCH ~24.7MB WRITE 16384KB. Branch A:
// MfmaUtil 75-95, main 44-55us. Branch B: main ~82 -> declare roofline.

#define NPTS 4194304
#define NBLK 2048
#define WPB 4                       // waves per block (256 threads)
#define NWAVES (NBLK * WPB)         // 8192
#define NTILES (NPTS / 32)          // 131072
#define TPW (NTILES / NWAVES)       // 16 tiles per wave
#define NMM 24
#define CH 4                        // chains (tiles) per asm iteration

typedef _Float16 h8 __attribute__((ext_vector_type(8)));

__device__ __forceinline__ unsigned pkrtz(float a, float b) {
    return __builtin_bit_cast(unsigned, __builtin_amdgcn_cvt_pkrtz(a, b));
}

// ---------------- prepack: fused A fragments, sigma-permuted K ---------------
// q=0: layer0 (k rows: x0,x1,x2 @ rr<3, bias col rr==3, pass A[10][rr==3]=1)
// q=1: layer1 dense (w1,b1, pass row 10)
// q=2+2l: fused block A: m0-9=Wr1^T|rr==10:Br1 ; m16-25=Wr2^T|rr==10:Br2+Br3;
//         m26,rr==10: 1 (ones pass)
// q=3+2l: W3 shifted: m16-25 = Wr3^T (rows 0-15 and 26 zero -> srcC passthru)
// q=22: layer8 dense (w8,b8, pass row 10)   q=23: out row m=0 (w9,b9)
__global__ __launch_bounds__(64) void prepack(
    const float* __restrict__ w0, const float* __restrict__ b0,
    const float* __restrict__ w1, const float* __restrict__ b1,
    const float* __restrict__ Wr1, const float* __restrict__ Br1,
    const float* __restrict__ Wr2, const float* __restrict__ Br2,
    const float* __restrict__ Wr3, const float* __restrict__ Br3,
    const float* __restrict__ w8, const float* __restrict__ b8,
    const float* __restrict__ w9, const float* __restrict__ b9,
    h8* __restrict__ tab)
{
    const int q = blockIdx.x, l = threadIdx.x;
    const int m = l & 31, g = l >> 5;
    h8 v;
#pragma unroll
    for (int j = 0; j < 8; ++j) {
        const int rr = (j & 3) + 8 * (j >> 2) + 4 * g;  // sigma(k)
        float a = 0.0f;
        if (q == 0) {
            if (m < 10 && rr < 3)        a = w0[rr * 10 + m];
            else if (m < 10 && rr == 3)  a = b0[m];
            else if (m == 10 && rr == 3) a = 1.0f;
        } else if (q == 1 || q == 22) {
            const float* W = (q == 1) ? w1 : w8;
            const float* B = (q == 1) ? b1 : b8;
            if (m < 10 && rr < 10)        a = W[rr * 10 + m];
            else if (m < 10 && rr == 10)  a = B[m];
            else if (m == 10 && rr == 10) a = 1.0f;
        } else if (q == 23) {
            if (m == 0 && rr < 10)       a = w9[rr];
            else if (m == 0 && rr == 10) a = b9[0];
        } else if (((q - 2) & 1) == 0) {           // fused W1|W2 block
            const int bl = (q - 2) >> 1;
            if (m < 10) {
                if (rr < 10)       a = Wr1[bl * 100 + rr * 10 + m];
                else if (rr == 10) a = Br1[bl * 10 + m];
            } else if (m >= 16 && m < 26) {
                if (rr < 10)       a = Wr2[bl * 100 + rr * 10 + (m - 16)];
                else if (rr == 10) a = Br2[bl * 10 + (m - 16)] + Br3[bl * 10 + (m - 16)];
            } else if (m == 26 && rr == 10) {
                a = 1.0f;                          // ones pass for next layer
            }
        } else {                                   // W3, output rows 16-25
            const int bl = (q - 3) >> 1;
            if (m >= 16 && m < 26 && rr < 10)
                a = Wr3[bl * 100 + rr * 10 + (m - 16)];
        }
        v[j] = (_Float16)a;
    }
    tab[q * 64 + l] = v;
}

// -------------------- asm text building blocks ------------------------------
// reg map: Z=v[16:31]; D0..3 = v[32:47],[48:63],[64:79],[80:95];
//          H0..3 = v[96:99],[100:103],[104:107],[108:111];
//          plane dbuf: PA12 v[112:115], PA3 v[116:119],
//                      PB12 v[120:123], PB3 v[124:127]

#define MM4_Z(P) \
  "v_mfma_f32_32x32x16_f16 v[32:47], " P ", v[96:99],   v[16:31]\n" \
  "v_mfma_f32_32x32x16_f16 v[48:63], " P ", v[100:103], v[16:31]\n" \
  "v_mfma_f32_32x32x16_f16 v[64:79], " P ", v[104:107], v[16:31]\n" \
  "v_mfma_f32_32x32x16_f16 v[80:95], " P ", v[108:111], v[16:31]\n"

#define MM4_ACC(P) \
  "v_mfma_f32_32x32x16_f16 v[32:47], " P ", v[96:99],   v[32:47]\n" \
  "v_mfma_f32_32x32x16_f16 v[48:63], " P ", v[100:103], v[48:63]\n" \
  "v_mfma_f32_32x32x16_f16 v[64:79], " P ", v[104:107], v[64:79]\n" \
  "v_mfma_f32_32x32x16_f16 v[80:95], " P ", v[108:111], v[80:95]\n"

#define RCLO_ALL \
  "v_cvt_pkrtz_f16_f32 v96,  v32, v33\n" \
  "v_cvt_pkrtz_f16_f32 v97,  v34, v35\n" \
  "v_cvt_pkrtz_f16_f32 v98,  v36, v37\n" \
  "v_cvt_pkrtz_f16_f32 v99,  v38, v39\n" \
  "v_pk_max_f16 v96, v96, 0\n" \
  "v_pk_max_f16 v97, v97, 0\n" \
  "v_pk_max_f16 v98, v98, 0\n" \
  "v_pk_max_f16 v99, v99, 0\n" \
  "v_cvt_pkrtz_f16_f32 v100, v48, v49\n" \
  "v_cvt_pkrtz_f16_f32 v101, v50, v51\n" \
  "v_cvt_pkrtz_f16_f32 v102, v52, v53\n" \
  "v_cvt_pkrtz_f16_f32 v103, v54, v55\n" \
  "v_pk_max_f16 v100, v100, 0\n" \
  "v_pk_max_f16 v101, v101, 0\n" \
  "v_pk_max_f16 v102, v102, 0\n" \
  "v_pk_max_f16 v103, v103, 0\n" \
  "v_cvt_pkrtz_f16_f32 v104, v64, v65\n" \
  "v_cvt_pkrtz_f16_f32 v105, v66, v67\n" \
  "v_cvt_pkrtz_f16_f32 v106, v68, v69\n" \
  "v_cvt_pkrtz_f16_f32 v107, v70, v71\n" \
  "v_pk_max_f16 v104, v104, 0\n" \
  "v_pk_max_f16 v105, v105, 0\n" \
  "v_pk_max_f16 v106, v106, 0\n" \
  "v_pk_max_f16 v107, v107, 0\n" \
  "v_cvt_pkrtz_f16_f32 v108, v80, v81\n" \
  "v_cvt_pkrtz_f16_f32 v109, v82, v83\n" \
  "v_cvt_pkrtz_f16_f32 v110, v84, v85\n" \
  "v_cvt_pkrtz_f16_f32 v111, v86, v87\n" \
  "v_pk_max_f16 v108, v108, 0\n" \
  "v_pk_max_f16 v109, v109, 0\n" \
  "v_pk_max_f16 v110, v110, 0\n" \
  "v_pk_max_f16 v111, v111, 0\n"

#define RCHI_ALL \
  "v_cvt_pkrtz_f16_f32 v96,  v40, v41\n" \
  "v_cvt_pkrtz_f16_f32 v97,  v42, v43\n" \
  "v_cvt_pkrtz_f16_f32 v98,  v44, v45\n" \
  "v_cvt_pkrtz_f16_f32 v99,  v46, v47\n" \
  "v_pk_max_f16 v96, v96, 0\n" \
  "v_pk_max_f16 v97, v97, 0\n" \
  "v_pk_max_f16 v98, v98, 0\n" \
  "v_pk_max_f16 v99, v99, 0\n" \
  "v_cvt_pkrtz_f16_f32 v100, v56, v57\n" \
  "v_cvt_pkrtz_f16_f32 v101, v58, v59\n" \
  "v_cvt_pkrtz_f16_f32 v102, v60, v61\n" \
  "v_cvt_pkrtz_f16_f32 v103, v62, v63\n" \
  "v_pk_max_f16 v100, v100, 0\n" \
  "v_pk_max_f16 v101, v101, 0\n" \
  "v_pk_max_f16 v102, v102, 0\n" \
  "v_pk_max_f16 v103, v103, 0\n" \
  "v_cvt_pkrtz_f16_f32 v104, v72, v73\n" \
  "v_cvt_pkrtz_f16_f32 v105, v74, v75\n" \
  "v_cvt_pkrtz_f16_f32 v106, v76, v77\n" \
  "v_cvt_pkrtz_f16_f32 v107, v78, v79\n" \
  "v_pk_max_f16 v104, v104, 0\n" \
  "v_pk_max_f16 v105, v105, 0\n" \
  "v_pk_max_f16 v106, v106, 0\n" \
  "v_pk_max_f16 v107, v107, 0\n" \
  "v_cvt_pkrtz_f16_f32 v108, v88, v89\n" \
  "v_cvt_pkrtz_f16_f32 v109, v90, v91\n" \
  "v_cvt_pkrtz_f16_f32 v110, v92, v93\n" \
  "v_cvt_pkrtz_f16_f32 v111, v94, v95\n" \
  "v_pk_max_f16 v108, v108, 0\n" \
  "v_pk_max_f16 v109, v109, 0\n" \
  "v_pk_max_f16 v110, v110, 0\n" \
  "v_pk_max_f16 v111, v111, 0\n"

// residual-block stage: consume (P12,P3); prefetch (F12,F3) into same bufs
#define ST_BLOCK(P12, P3, F12, F3) \
  "s_waitcnt lgkmcnt(2)\n" \
  MM4_Z(P12) \
  "s_nop 7\ns_nop 7\ns_nop 2\n" \
  RCLO_ALL \
  "s_nop 1\n" \
  MM4_ACC(P3) \
  "ds_read_b128 " P12 ", %[ad] offset:" F12 "\n" \
  "ds_read_b128 " P3  ", %[ad] offset:" F3  "\n" \
  "s_nop 7\ns_nop 6\n" \
  RCHI_ALL \
  "s_nop 1\n"

#define ST_BLOCK_NOPF(P12, P3) \
  "s_waitcnt lgkmcnt(2)\n" \
  MM4_Z(P12) \
  "s_nop 7\ns_nop 7\ns_nop 2\n" \
  RCLO_ALL \
  "s_nop 1\n" \
  MM4_ACC(P3) \
  "s_nop 7\ns_nop 7\ns_nop 2\n" \
  RCHI_ALL \
  "s_nop 1\n"

// first stage: l0 (plane0, PA12) + l1 (plane1, PA3); prefetch planes 4,5->PA
#define ST_FIRST \
  "s_waitcnt lgkmcnt(2)\n" \
  MM4_Z("v[112:115]") \
  "s_nop 7\ns_nop 7\ns_nop 2\n" \
  RCLO_ALL \
  "s_nop 1\n" \
  MM4_Z("v[116:119]") \
  "ds_read_b128 v[112:115], %[ad] offset:4096\n" \
  "ds_read_b128 v[116:119], %[ad] offset:5120\n" \
  "s_nop 7\ns_nop 6\n" \
  RCLO_ALL \
  "s_nop 1\n"

// last stage: l8 (plane22, PB12) + l9 (plane23, PB3); emit row0 of each D
#define ST_LAST \
  "s_waitcnt lgkmcnt(0)\n" \
  MM4_Z("v[120:123]") \
  "s_nop 7\ns_nop 7\ns_nop 2\n" \
  RCLO_ALL \
  "s_nop 1\n" \
  MM4_Z("v[124:127]") \
  "s_nop 7\ns_nop 7\ns_nop 2\n" \
  "v_mov_b32 %[o0], v32\n" \
  "v_mov_b32 %[o1], v48\n" \
  "v_mov_b32 %[o2], v64\n" \
  "v_mov_b32 %[o3], v80\n"

#define PROLOG \
  "v_mov_b32 v16, 0\n" "v_mov_b32 v17, 0\n" "v_mov_b32 v18, 0\n" "v_mov_b32 v19, 0\n" \
  "v_mov_b32 v20, 0\n" "v_mov_b32 v21, 0\n" "v_mov_b32 v22, 0\n" "v_mov_b32 v23, 0\n" \
  "v_mov_b32 v24, 0\n" "v_mov_b32 v25, 0\n" "v_mov_b32 v26, 0\n" "v_mov_b32 v27, 0\n" \
  "v_mov_b32 v28, 0\n" "v_mov_b32 v29, 0\n" "v_mov_b32 v30, 0\n" "v_mov_b32 v31, 0\n" \
  "v_mov_b32 v96,  %[g0]\n" "v_mov_b32 v97,  %[g1]\n" \
  "v_mov_b32 v98,  0\n"     "v_mov_b32 v99,  0\n" \
  "v_mov_b32 v100, %[g2]\n" "v_mov_b32 v101, %[g3]\n" \
  "v_mov_b32 v102, 0\n"     "v_mov_b32 v103, 0\n" \
  "v_mov_b32 v104, %[g4]\n" "v_mov_b32 v105, %[g5]\n" \
  "v_mov_b32 v106, 0\n"     "v_mov_b32 v107, 0\n" \
  "v_mov_b32 v108, %[g6]\n" "v_mov_b32 v109, %[g7]\n" \
  "v_mov_b32 v110, 0\n"     "v_mov_b32 v111, 0\n" \
  "ds_read_b128 v[112:115], %[ad] offset:0\n" \
  "ds_read_b128 v[116:119], %[ad] offset:1024\n" \
  "ds_read_b128 v[120:123], %[ad] offset:2048\n" \
  "ds_read_b128 v[124:127], %[ad] offset:3072\n"

#define CHAIN_ASM \
  PROLOG \
  ST_FIRST \
  ST_BLOCK("v[120:123]", "v[124:127]",  "6144",  "7168") \
  ST_BLOCK("v[112:115]", "v[116:119]",  "8192",  "9216") \
  ST_BLOCK("v[120:123]", "v[124:127]", "10240", "11264") \
  ST_BLOCK("v[112:115]", "v[116:119]", "12288", "13312") \
  ST_BLOCK("v[120:123]", "v[124:127]", "14336", "15360") \
  ST_BLOCK("v[112:115]", "v[116:119]", "16384", "17408") \
  ST_BLOCK("v[120:123]", "v[124:127]", "18432", "19456") \
  ST_BLOCK("v[112:115]", "v[116:119]", "20480", "21504") \
  ST_BLOCK("v[120:123]", "v[124:127]", "22528", "23552") \
  ST_BLOCK_NOPF("v[112:115]", "v[116:119]") \
  ST_LAST

#define VCLOB \
  "v16","v17","v18","v19","v20","v21","v22","v23", \
  "v24","v25","v26","v27","v28","v29","v30","v31", \
  "v32","v33","v34","v35","v36","v37","v38","v39", \
  "v40","v41","v42","v43","v44","v45","v46","v47", \
  "v48","v49","v50","v51","v52","v53","v54","v55", \
  "v56","v57","v58","v59","v60","v61","v62","v63", \
  "v64","v65","v66","v67","v68","v69","v70","v71", \
  "v72","v73","v74","v75","v76","v77","v78","v79", \
  "v80","v81","v82","v83","v84","v85","v86","v87", \
  "v88","v89","v90","v91","v92","v93","v94","v95", \
  "v96","v97","v98","v99","v100","v101","v102","v103", \
  "v104","v105","v106","v107","v108","v109","v110","v111", \
  "v112","v113","v114","v115","v116","v117","v118","v119", \
  "v120","v121","v122","v123","v124","v125","v126","v127"

// ---- main kernel: 4-chain asm 24-stage chain, LDS weight table -------------
__global__ __launch_bounds__(256, 3) void resnet_fwd(
    const float* __restrict__ x,
    const h8* __restrict__ tab,
    float* __restrict__ out)
{
    // stage the 24 A-fragment planes (24*64*16B = 24.6 KB) once per block
    __shared__ h8 sA[NMM * 64];
    for (int i = threadIdx.x; i < NMM * 64; i += 256) sA[i] = tab[i];
    __syncthreads();

    const int lane = threadIdx.x & 63;
    const int wv = blockIdx.x * WPB + (threadIdx.x >> 6);
    const int col = lane & 31;
    const bool lo = lane < 32;
    const float m = lo ? 1.0f : 0.0f;

    const unsigned ad = (unsigned)(size_t)(&sA[lane]);   // LDS byte address

    const long p0 = (long)wv * TPW * 32;          // first point index of wave
    const float* px = x + (p0 + col) * 3;         // per-lane x pointer
    float* po = out + p0 + col;                   // per-lane out pointer

    // x for iteration 0 (branchless: col valid for all lanes)
    float xa[CH * 3];
#pragma unroll
    for (int c = 0; c < CH; ++c) {
        xa[c * 3 + 0] = px[c * 96 + 0];
        xa[c * 3 + 1] = px[c * 96 + 1];
        xa[c * 3 + 2] = px[c * 96 + 2];
    }

#pragma unroll 1
    for (int t = 0; t < TPW; t += CH) {
        // build B words for 4 chains (hi lanes zeroed via m / selects)
        unsigned g[2 * CH];
#pragma unroll
        for (int c = 0; c < CH; ++c) {
            float a0 = lo ? xa[c * 3 + 0] : 0.0f;
            float a1 = lo ? xa[c * 3 + 1] : 0.0f;
            float a2 = lo ? xa[c * 3 + 2] : 0.0f;
            g[2 * c + 0] = pkrtz(a0, a1);
            g[2 * c + 1] = pkrtz(a2, m);
        }

        // issue next iteration's x loads; they land under the ~2.5k-cyc asm
        const float* pn = px + CH * 96;
        float nx[CH * 3];
#pragma unroll
        for (int i = 0; i < CH * 3; ++i) nx[i] = 0.0f;
        if (t + CH < TPW) {
#pragma unroll
            for (int c = 0; c < CH; ++c) {
                nx[c * 3 + 0] = pn[c * 96 + 0];
                nx[c * 3 + 1] = pn[c * 96 + 1];
                nx[c * 3 + 2] = pn[c * 96 + 2];
            }
        }

        float o0, o1, o2, o3;
        asm volatile(
            CHAIN_ASM
            : [o0] "=v"(o0), [o1] "=v"(o1), [o2] "=v"(o2), [o3] "=v"(o3)
            : [g0] "v"(g[0]), [g1] "v"(g[1]), [g2] "v"(g[2]), [g3] "v"(g[3]),
              [g4] "v"(g[4]), [g5] "v"(g[5]), [g6] "v"(g[6]), [g7] "v"(g[7]),
              [ad] "v"(ad)
            : VCLOB);

        if (lo) { po[0] = o0; po[32] = o1; po[64] = o2; po[96] = o3; }

        px = pn;
        po += CH * 32;
#pragma unroll
        for (int i = 0; i < CH * 3; ++i) xa[i] = nx[i];
    }
}

extern "C" void kernel_launch(void* const* d_in, const int* in_sizes, int n_in,
                              void* d_out, int out_size, void* d_ws, size_t ws_size,
                              hipStream_t stream)
{
    const float* x   = (const float*)d_in[0];
    const float* w0  = (const float*)d_in[1];
    const float* b0  = (const float*)d_in[2];
    const float* w1  = (const float*)d_in[3];
    const float* b1  = (const float*)d_in[4];
    const float* Wr1 = (const float*)d_in[5];
    const float* Br1 = (const float*)d_in[6];
    const float* Wr2 = (const float*)d_in[7];
    const float* Br2 = (const float*)d_in[8];
    const float* Wr3 = (const float*)d_in[9];
    const float* Br3 = (const float*)d_in[10];
    const float* w8  = (const float*)d_in[11];
    const float* b8  = (const float*)d_in[12];
    const float* w9  = (const float*)d_in[13];
    const float* b9  = (const float*)d_in[14];
    float* out = (float*)d_out;
    h8* tab = (h8*)d_ws;   // 24 * 64 * 16B = 24.6 KB scratch

    hipLaunchKernelGGL(prepack, dim3(NMM), dim3(64), 0, stream,
                       w0, b0, w1, b1, Wr1, Br1, Wr2, Br2, Wr3, Br3,
                       w8, b8, w9, b9, tab);

    hipLaunchKernelGGL(resnet_fwd, dim3(NBLK), dim3(256), 0, stream,
                       x, (const h8*)tab, out);
}

// Round 11
// 174.124 us; speedup vs baseline: 1.0049x; 1.0049x over previous
//
#include <hip/hip_runtime.h>

// ResidualNetwork forward, MI355X (gfx950).
// Round 31: TERMINAL REVERT-TO-BEST. r30's discriminating experiment (4-chain
// asm, MFMAs back-to-back, latency filled with real VALU, absmax 0) landed
// 86.9us @ MfmaUtil 48% -> H-B confirmed: effective MFMA slot in this mixed
// fresh-C/fresh-D stream is ~64 cyc, not the 32-cyc in-place-accumulate
// ubench number. Ceiling arithmetic: 3072 MFMA/SIMD x 64 cyc = 196k cyc =
// 82us == the wall measured across 11 rounds (80.2-87) regardless of
// occupancy (2.2-8 w/SIMD), chains (2-4), operand home (LDS/reg), scheduler
// (7 compiler forms, 2 hand-asm). Demand-side is provably minimal: 24
// MFMA/32pts (m 27/32, n 32/32, k 11/16; 16x16x32 repack = 78 cyc/32pts,
// worse). Deep-serial net -> fresh-D unavoidable. This round restores the
// best-measured kernel (r27 form: LDS table, ILP2, (256,4), branchless
// B-build; main 82.0-82.4us, harness 172.98us). Roofline declared next.
// Gates (reproduction): VGPR 40; LDS 24576; Occ 44-46; Mfma 52-54; main
// 82-83.5us; FETCH ~24.7MB WRITE 16384KB; absmax 0.

#define NPTS 4194304
#define NBLK 2048
#define WPB 4                       // waves per block (256 threads)
#define NWAVES (NBLK * WPB)         // 8192
#define NTILES (NPTS / 32)          // 131072
#define TPW (NTILES / NWAVES)       // 16 tiles per wave
#define NMM 24
#define ILP 2

typedef _Float16 h8 __attribute__((ext_vector_type(8)));
typedef float v16f __attribute__((ext_vector_type(16)));
typedef unsigned u4v __attribute__((ext_vector_type(4)));

// T19 masks: MFMA=0x8, VALU=0x2 (kept from r27's best-measured build; proven
// harmless -- identical codegen/counters to r21's form without them)
#define SGB_MFMA(n) __builtin_amdgcn_sched_group_barrier(0x8, n, 0)
#define SGB_VALU(n) __builtin_amdgcn_sched_group_barrier(0x2, n, 0)

__device__ __forceinline__ v16f mm(h8 a, h8 b, v16f c) {
    return __builtin_amdgcn_mfma_f32_32x32x16_f16(a, b, c, 0, 0, 0);
}
__device__ __forceinline__ unsigned pkrtz(float a, float b) {
    return __builtin_bit_cast(unsigned, __builtin_amdgcn_cvt_pkrtz(a, b));
}
// relu on packed f16: 4x v_pk_max_f16
__device__ __forceinline__ h8 relu8(h8 h) {
    h8 z = {0, 0, 0, 0, 0, 0, 0, 0};
    return __builtin_elementwise_max(h, z);
}
// pack+relu of D regs 0-7 (rows sigma(k)): B fragment, sigma order
__device__ __forceinline__ h8 rc_lo(v16f d) {
    u4v u;
    u.x = pkrtz(d[0], d[1]); u.y = pkrtz(d[2], d[3]);
    u.z = pkrtz(d[4], d[5]); u.w = pkrtz(d[6], d[7]);
    return relu8(__builtin_bit_cast(h8, u));
}
// pack+relu of D regs 8-15 (rows 16+sigma(k)): same sigma order
__device__ __forceinline__ h8 rc_hi(v16f d) {
    u4v u;
    u.x = pkrtz(d[8], d[9]);   u.y = pkrtz(d[10], d[11]);
    u.z = pkrtz(d[12], d[13]); u.w = pkrtz(d[14], d[15]);
    return relu8(__builtin_bit_cast(h8, u));
}

// ---------------- prepack: fused A fragments, sigma-permuted K ---------------
// q=0: layer0 (k rows: x0,x1,x2 @ rr<3, bias col rr==3, pass A[10][rr==3]=1)
// q=1: layer1 dense (w1,b1, pass row 10)
// q=2+2l: fused block A: m0-9=Wr1^T|rr==10:Br1 ; m16-25=Wr2^T|rr==10:Br2+Br3;
//         m26,rr==10: 1 (ones pass)
// q=3+2l: W3 shifted: m16-25 = Wr3^T (rows 0-15 and 26 zero -> srcC passthru)
// q=22: layer8 dense (w8,b8, pass row 10)   q=23: out row m=0 (w9,b9)
__global__ __launch_bounds__(64) void prepack(
    const float* __restrict__ w0, const float* __restrict__ b0,
    const float* __restrict__ w1, const float* __restrict__ b1,
    const float* __restrict__ Wr1, const float* __restrict__ Br1,
    const float* __restrict__ Wr2, const float* __restrict__ Br2,
    const float* __restrict__ Wr3, const float* __restrict__ Br3,
    const float* __restrict__ w8, const float* __restrict__ b8,
    const float* __restrict__ w9, const float* __restrict__ b9,
    h8* __restrict__ tab)
{
    const int q = blockIdx.x, l = threadIdx.x;
    const int m = l & 31, g = l >> 5;
    h8 v;
#pragma unroll
    for (int j = 0; j < 8; ++j) {
        const int rr = (j & 3) + 8 * (j >> 2) + 4 * g;  // sigma(k)
        float a = 0.0f;
        if (q == 0) {
            if (m < 10 && rr < 3)        a = w0[rr * 10 + m];
            else if (m < 10 && rr == 3)  a = b0[m];
            else if (m == 10 && rr == 3) a = 1.0f;
        } else if (q == 1 || q == 22) {
            const float* W = (q == 1) ? w1 : w8;
            const float* B = (q == 1) ? b1 : b8;
            if (m < 10 && rr < 10)        a = W[rr * 10 + m];
            else if (m < 10 && rr == 10)  a = B[m];
            else if (m == 10 && rr == 10) a = 1.0f;
        } else if (q == 23) {
            if (m == 0 && rr < 10)       a = w9[rr];
            else if (m == 0 && rr == 10) a = b9[0];
        } else if (((q - 2) & 1) == 0) {           // fused W1|W2 block
            const int bl = (q - 2) >> 1;
            if (m < 10) {
                if (rr < 10)       a = Wr1[bl * 100 + rr * 10 + m];
                else if (rr == 10) a = Br1[bl * 10 + m];
            } else if (m >= 16 && m < 26) {
                if (rr < 10)       a = Wr2[bl * 100 + rr * 10 + (m - 16)];
                else if (rr == 10) a = Br2[bl * 10 + (m - 16)] + Br3[bl * 10 + (m - 16)];
            } else if (m == 26 && rr == 10) {
                a = 1.0f;                          // ones pass for next layer
            }
        } else {                                   // W3, output rows 16-25
            const int bl = (q - 3) >> 1;
            if (m >= 16 && m < 26 && rr < 10)
                a = Wr3[bl * 100 + rr * 10 + (m - 16)];
        }
        v[j] = (_Float16)a;
    }
    tab[q * 64 + l] = v;
}

// ---- main kernel: fused 24-MFMA chain, LDS weight table, ILP2 --------------
__global__ __launch_bounds__(256, 4) void resnet_fwd(
    const float* __restrict__ x,
    const h8* __restrict__ tab,
    float* __restrict__ out)
{
    // stage the 24 A-fragment planes (24*64*16B = 24.6 KB) once per block
    __shared__ h8 sA[NMM * 64];
    for (int i = threadIdx.x; i < NMM * 64; i += 256) sA[i] = tab[i];
    __syncthreads();

    const int lane = threadIdx.x & 63;
    const int wv = blockIdx.x * WPB + (threadIdx.x >> 6);
    const int col = lane & 31;
    const bool lo = lane < 32;

    // resident zero srcC
    v16f zero;
#pragma unroll
    for (int j = 0; j < 16; ++j) zero[j] = 0.0f;
    asm volatile("" : "+v"(zero));

    const long p0 = (long)wv * TPW * 32;          // first point index of wave
    const float* px = x + (p0 + col) * 3;         // per-lane x pointer
    float* po = out + p0 + col;                   // per-lane out pointer

    for (int t = 0; t < TPW; t += ILP) {
        // opaque lane index: stops LICM hoisting all 24 planes into regs
        int ln = lane;
        asm volatile("" : "+v"(ln));
        const h8* wp = &sA[ln];

        // layer-0 B: branchless loads (col = lane&31 is valid for ALL lanes;
        // hi lanes zeroed by selects)
        h8 hh[ILP];
#pragma unroll
        for (int c = 0; c < ILP; ++c) {
            float a0 = px[c * 96 + 0];
            float a1 = px[c * 96 + 1];
            float a2 = px[c * 96 + 2];
            a0 = lo ? a0 : 0.0f;
            a1 = lo ? a1 : 0.0f;
            a2 = lo ? a2 : 0.0f;
            u4v u;
            u.x = pkrtz(a0, a1); u.y = pkrtz(a2, lo ? 1.0f : 0.0f);
            u.z = 0u; u.w = 0u;
            hh[c] = __builtin_bit_cast(h8, u);
        }

        // layer 0
        {
            h8 a0 = wp[0 * 64];
            v16f d[ILP];
#pragma unroll
            for (int c = 0; c < ILP; ++c) d[c] = mm(a0, hh[c], zero);
            SGB_MFMA(2);
#pragma unroll
            for (int c = 0; c < ILP; ++c) hh[c] = rc_lo(d[c]);
            SGB_VALU(16);
        }
        // layer 1
        {
            h8 a1 = wp[1 * 64];
            v16f d[ILP];
#pragma unroll
            for (int c = 0; c < ILP; ++c) d[c] = mm(a1, hh[c], zero);
            SGB_MFMA(2);
#pragma unroll
            for (int c = 0; c < ILP; ++c) hh[c] = rc_lo(d[c]);
            SGB_VALU(16);
        }

        // residual blocks: [mm12 x2][rc_lo x2][mm3 x2][rc_hi x2] per block
#pragma unroll
        for (int bl = 0; bl < 10; ++bl) {
            h8 a12 = wp[(2 + 2 * bl) * 64];
            h8 a3  = wp[(3 + 2 * bl) * 64];
            v16f d12[ILP];
#pragma unroll
            for (int c = 0; c < ILP; ++c) d12[c] = mm(a12, hh[c], zero);
            SGB_MFMA(2);
            h8 t1[ILP];
#pragma unroll
            for (int c = 0; c < ILP; ++c) t1[c] = rc_lo(d12[c]);
            SGB_VALU(16);
#pragma unroll
            for (int c = 0; c < ILP; ++c) d12[c] = mm(a3, t1[c], d12[c]);
            SGB_MFMA(2);
#pragma unroll
            for (int c = 0; c < ILP; ++c) hh[c] = rc_hi(d12[c]);
            SGB_VALU(16);
        }

        // layer 8
        {
            h8 a8 = wp[22 * 64];
            v16f d[ILP];
#pragma unroll
            for (int c = 0; c < ILP; ++c) d[c] = mm(a8, hh[c], zero);
            SGB_MFMA(2);
#pragma unroll
            for (int c = 0; c < ILP; ++c) hh[c] = rc_lo(d[c]);
            SGB_VALU(16);
        }

        // output layer: D row 0 (lanes 0-31, reg 0) = result for 32 points
        {
            h8 a9 = wp[23 * 64];
            v16f d[ILP];
#pragma unroll
            for (int c = 0; c < ILP; ++c) d[c] = mm(a9, hh[c], zero);
            SGB_MFMA(2);
#pragma unroll
            for (int c = 0; c < ILP; ++c)
                if (lo) po[c * 32] = d[c][0];
        }

        px += ILP * 96;
        po += ILP * 32;
    }
}

extern "C" void kernel_launch(void* const* d_in, const int* in_sizes, int n_in,
                              void* d_out, int out_size, void* d_ws, size_t ws_size,
                              hipStream_t stream)
{
    const float* x   = (const float*)d_in[0];
    const float* w0  = (const float*)d_in[1];
    const float* b0  = (const float*)d_in[2];
    const float* w1  = (const float*)d_in[3];
    const float* b1  = (const float*)d_in[4];
    const float* Wr1 = (const float*)d_in[5];
    const float* Br1 = (const float*)d_in[6];
    const float* Wr2 = (const float*)d_in[7];
    const float* Br2 = (const float*)d_in[8];
    const float* Wr3 = (const float*)d_in[9];
    const float* Br3 = (const float*)d_in[10];
    const float* w8  = (const float*)d_in[11];
    const float* b8  = (const float*)d_in[12];
    const float* w9  = (const float*)d_in[13];
    const float* b9  = (const float*)d_in[14];
    float* out = (float*)d_out;
    h8* tab = (h8*)d_ws;   // 24 * 64 * 16B = 24.6 KB scratch

    hipLaunchKernelGGL(prepack, dim3(NMM), dim3(64), 0, stream,
                       w0, b0, w1, b1, Wr1, Br1, Wr2, Br2, Wr3, Br3,
                       w8, b8, w9, b9, tab);

    hipLaunchKernelGGL(resnet_fwd, dim3(NBLK), dim3(256), 0, stream,
                       x, (const h8*)tab, out);
}